// Round 3
// baseline (290.922 us; speedup 1.0000x reference)
//
#include <hip/hip_runtime.h>
#include <stdint.h>

// AttentionBlock: B=32, C=512, H=W=32 (N=1024), fp32 in/out.
//   cvt weights -> bf16 ; transpose x -> Xt[B,N,C] bf16
//   Q = (Xt*Wq^T + bq) * C^-0.5 * log2e   [B*N, C]  (softmax in exp2 domain)
//   K = Xt*Wk^T + bk              [B*N, C]
//   V = Wv*Xt_b^T + bv            [B][C][N]
//   H = flash_attn(Q,K,V)         [B][N][C]  (swapped-QK^T, dbuf, counted vmcnt)
//   out = Wo*H_b^T + bo + x       [B][C][N] fp32

#define CD 512
#define NSP 1024

using bf16x8 = __attribute__((ext_vector_type(8))) short;
using f32x4  = __attribute__((ext_vector_type(4))) float;

__device__ __forceinline__ float bf2f(unsigned short u) {
    union { unsigned int i; float f; } v; v.i = ((unsigned int)u) << 16; return v.f;
}
__device__ __forceinline__ unsigned short f2bf(float f) {
    union { float f; unsigned int i; } v; v.f = f;
    unsigned int r = v.i + 0x7FFFu + ((v.i >> 16) & 1u);
    return (unsigned short)(r >> 16);
}
// async global->LDS, 16B per lane; lds dest = base + lane*16 (wave-uniform base)
__device__ __forceinline__ void gl_lds16(const unsigned short* g, unsigned short* l) {
    __builtin_amdgcn_global_load_lds(
        (const __attribute__((address_space(1))) void*)g,
        (__attribute__((address_space(3))) void*)l, 16, 0, 0);
}

__global__ __launch_bounds__(256) void cvt_w(const float* __restrict__ in,
                                             unsigned short* __restrict__ out, int n) {
    int i = blockIdx.x * 256 + threadIdx.x;
    if (i < n) out[i] = f2bf(in[i]);
}

// x [B][C][N] f32 -> xt [B][N][C] bf16
__global__ __launch_bounds__(256) void transpose_x(const float* __restrict__ x,
                                                   unsigned short* __restrict__ xt) {
    __shared__ float t[32][33];
    int b = blockIdx.z;
    int n0 = blockIdx.x * 32, c0 = blockIdx.y * 32;
    const float* xb = x + (size_t)b * CD * NSP;
    unsigned short* xtb = xt + (size_t)b * NSP * CD;
    int tx = threadIdx.x, ty = threadIdx.y;
    #pragma unroll
    for (int i = 0; i < 4; ++i)
        t[ty + i * 8][tx] = xb[(size_t)(c0 + ty + i * 8) * NSP + n0 + tx];
    __syncthreads();
    #pragma unroll
    for (int i = 0; i < 4; ++i)
        xtb[(size_t)(n0 + ty + i * 8) * CD + c0 + tx] = f2bf(t[tx][ty + i * 8]);
}

// C[m][n] = alpha * (sum_k A[m][k]*B[n][k] + bias) (+resid) ; bf16 in
// 128x128 tile, BK=64, 4 waves. Double-buffered global_load_lds staging with
// counted vmcnt(8) + raw s_barrier (2-phase pipeline); pre-swizzled source,
// linear LDS dest, XOR on read.
template<int BIAS_MODE, bool RESID, bool OUT_F32>
__global__ __launch_bounds__(256)
void gemm_bt(const unsigned short* __restrict__ A,
             const unsigned short* __restrict__ B,
             void* __restrict__ Cv,
             const float* __restrict__ bias,
             const float* __restrict__ resid,
             int K, int lda, int ldb, int ldc,
             long sA, long sB, long sC, long sR, float alpha)
{
    __shared__ __align__(16) unsigned short As[2][128 * 64];
    __shared__ __align__(16) unsigned short Bs[2][128 * 64];

    const int z = blockIdx.z;
    const unsigned short* Ab = A + (size_t)z * sA + (size_t)blockIdx.y * 128 * lda;
    const unsigned short* Bb = B + (size_t)z * sB + (size_t)blockIdx.x * 128 * ldb;

    const int t = threadIdx.x;
    const int lane = t & 63;
    const int wave = t >> 6;
    const int wr = wave >> 1, wc = wave & 1;
    const int lr = lane & 15, lk = lane >> 4;

    f32x4 acc[4][4] = {};

    const int KT = K >> 6;
    auto stage = [&](int kt, int buf) {
        int k0 = kt << 6;
        #pragma unroll
        for (int i = 0; i < 4; ++i) {
            int rb = i * 32 + wave * 8;
            int row = rb + (lane >> 3);
            int ch = (lane & 7) ^ (row & 7);
            gl_lds16(Ab + (size_t)row * lda + k0 + ch * 8, &As[buf][rb * 64]);
            gl_lds16(Bb + (size_t)row * ldb + k0 + ch * 8, &Bs[buf][rb * 64]);
        }
    };
    stage(0, 0);
    for (int kt = 0; kt < KT; ++kt) {
        int cur = kt & 1;
        if (kt + 1 < KT) {
            stage(kt + 1, cur ^ 1);
            asm volatile("s_waitcnt vmcnt(8)" ::: "memory");
        } else {
            asm volatile("s_waitcnt vmcnt(0)" ::: "memory");
        }
        __builtin_amdgcn_s_barrier();
        const unsigned short* Ac = &As[cur][0];
        const unsigned short* Bc = &Bs[cur][0];
        #pragma unroll
        for (int kk = 0; kk < 2; ++kk) {
            bf16x8 af[4], bfr[4];
            #pragma unroll
            for (int f = 0; f < 4; ++f) {
                int arow = wr * 64 + f * 16 + lr;
                af[f] = *(const bf16x8*)&Ac[(arow << 6) + ((((kk << 2) | lk) ^ (arow & 7)) << 3)];
                int brow = wc * 64 + f * 16 + lr;
                bfr[f] = *(const bf16x8*)&Bc[(brow << 6) + ((((kk << 2) | lk) ^ (brow & 7)) << 3)];
            }
            #pragma unroll
            for (int fm = 0; fm < 4; ++fm)
                #pragma unroll
                for (int fn = 0; fn < 4; ++fn)
                    acc[fm][fn] = __builtin_amdgcn_mfma_f32_16x16x32_bf16(
                        af[fm], bfr[fn], acc[fm][fn], 0, 0, 0);
        }
        asm volatile("s_waitcnt lgkmcnt(0)" ::: "memory");
        __builtin_amdgcn_s_barrier();
    }

    const int m0 = blockIdx.y * 128;
    const int n0 = blockIdx.x * 128;
    float* Cf = (float*)Cv + (size_t)z * sC;
    unsigned short* Ch = (unsigned short*)Cv + (size_t)z * sC;
    const float* rp = resid ? resid + (size_t)z * sR : nullptr;

    #pragma unroll
    for (int fm = 0; fm < 4; ++fm) {
        #pragma unroll
        for (int fn = 0; fn < 4; ++fn) {
            int col = n0 + wc * 64 + fn * 16 + lr;          // D col = lane&15
            int rowb = m0 + wr * 64 + fm * 16 + lk * 4;     // D row = 4*(lane>>4)+j
            #pragma unroll
            for (int j = 0; j < 4; ++j) {
                int row = rowb + j;
                float v = acc[fm][fn][j];
                if (BIAS_MODE == 1) v += bias[col];
                if (BIAS_MODE == 2) v += bias[row];
                v *= alpha;
                if (RESID) v += rp[(size_t)row * ldc + col];
                if (OUT_F32) Cf[(size_t)row * ldc + col] = v;
                else         Ch[(size_t)row * ldc + col] = f2bf(v);
            }
        }
    }
}

// Fused attention: per block = 1 batch x 128 q-rows (8 waves x 16 rows).
// Swapped QK^T: S^T = mfma(K, Q) so each lane's S values all belong to one
// q-row (q = lane&15) -> scalar m/l, 2-shfl reductions, b64 P-pack.
// kv-tile 32, K/V double-buffered, counted vmcnt(8), raw s_barrier.
__global__ __launch_bounds__(512, 2)
void flash_attn(const unsigned short* __restrict__ Q,
                const unsigned short* __restrict__ Kg,
                const unsigned short* __restrict__ Vg,
                unsigned short* __restrict__ H)
{
    __shared__ __align__(16) unsigned short Ks[2][32 * 512];  // 2x32 KB
    __shared__ __align__(16) unsigned short Vs[2][512 * 32];  // 2x32 KB
    __shared__ __align__(16) unsigned short Ps[8][16 * 72];   // 18 KB, pitch 144B

    // XCD-affinity decode: keep one batch's K/V on one XCD's L2
    const int p = blockIdx.x;
    const int b  = ((p >> 6) << 3) + (p & 7);
    const int qt = (p >> 3) & 7;

    const int tid = threadIdx.x;
    const int w = tid >> 6, lane = tid & 63;
    const int lr = lane & 15, lk = lane >> 4;
    const int q0 = qt * 128 + w * 16;

    // Q B-operand frags: lane holds Q[q0+lr][ck*32 + lk*8 + e]
    bf16x8 qf[16];
    const unsigned short* qp = Q + ((size_t)b * NSP + q0 + lr) * CD + lk * 8;
    #pragma unroll
    for (int ck = 0; ck < 16; ++ck) qf[ck] = *(const bf16x8*)(qp + ck * 32);

    f32x4 o[32] = {};
    float m = -3.0e38f, l = 0.f;

    const unsigned short* Kb = Kg + (size_t)b * NSP * CD;
    const unsigned short* Vb = Vg + (size_t)b * CD * NSP;

    auto stageK = [&](int t, int buf) {
        int kv0 = t * 32;
        #pragma unroll
        for (int i = 0; i < 4; ++i) {
            int row = w * 4 + i;
            int ch = lane ^ (row & 7);
            gl_lds16(Kb + (size_t)(kv0 + row) * CD + ch * 8, &Ks[buf][row * 512]);
        }
    };
    auto stageV = [&](int t, int buf) {
        int kv0 = t * 32;
        #pragma unroll
        for (int i = 0; i < 4; ++i) {
            int rb = w * 64 + i * 16;
            int row = rb + (lane >> 2);
            int pos = lane & 3;
            int src = (pos - ((row >> 1) & 3)) & 3;   // rotate: read undoes it
            gl_lds16(Vb + (size_t)row * NSP + kv0 + src * 8, &Vs[buf][rb * 32]);
        }
    };
    stageK(0, 0); stageV(0, 0);

    for (int t = 0; t < 32; ++t) {
        const int cur = t & 1;
        if (t < 31) {
            stageK(t + 1, cur ^ 1); stageV(t + 1, cur ^ 1);
            asm volatile("s_waitcnt vmcnt(8)" ::: "memory");
        } else {
            asm volatile("s_waitcnt vmcnt(0)" ::: "memory");
        }
        __builtin_amdgcn_s_barrier();

        // S^T[kv][q] = sum_k K[kv][k] * Q[q][k]; kv = fm*16 + 4*lk + j, q = lr
        f32x4 s[2] = {};
        const unsigned short* Kc = &Ks[cur][0];
        __builtin_amdgcn_s_setprio(1);
        #pragma unroll
        for (int st = 0; st < 16; ++st) {
            #pragma unroll
            for (int fm = 0; fm < 2; ++fm) {
                int r = fm * 16 + lr;
                int cs = (st * 4 + lk) ^ (r & 7);
                bf16x8 kf = *(const bf16x8*)&Kc[r * 512 + cs * 8];
                s[fm] = __builtin_amdgcn_mfma_f32_16x16x32_bf16(kf, qf[st], s[fm], 0, 0, 0);
            }
        }
        __builtin_amdgcn_s_setprio(0);

        // online softmax in exp2 domain; all 8 lane-values belong to q = lr
        float pm = fmaxf(fmaxf(fmaxf(s[0][0], s[0][1]), fmaxf(s[0][2], s[0][3])),
                         fmaxf(fmaxf(s[1][0], s[1][1]), fmaxf(s[1][2], s[1][3])));
        pm = fmaxf(pm, __shfl_xor(pm, 16));
        pm = fmaxf(pm, __shfl_xor(pm, 32));
        if (!__all(pm - m <= 8.0f)) {      // T13 defer-max
            float mn = fmaxf(m, pm);
            float sc = exp2f(m - mn);
            m = mn; l *= sc;
            float f0 = __shfl(sc, 4 * lk + 0);
            float f1 = __shfl(sc, 4 * lk + 1);
            float f2 = __shfl(sc, 4 * lk + 2);
            float f3 = __shfl(sc, 4 * lk + 3);
            #pragma unroll
            for (int ns = 0; ns < 32; ++ns) {
                o[ns][0] *= f0; o[ns][1] *= f1; o[ns][2] *= f2; o[ns][3] *= f3;
            }
        }
        float pe[2][4]; float rs = 0.f;
        #pragma unroll
        for (int fm = 0; fm < 2; ++fm)
            #pragma unroll
            for (int j = 0; j < 4; ++j) {
                pe[fm][j] = exp2f(s[fm][j] - m);
                rs += pe[fm][j];
            }
        rs += __shfl_xor(rs, 16);
        rs += __shfl_xor(rs, 32);
        l += rs;

        // pack P -> Ps[q=lr][kv], b64 writes (conflict-free at 144B pitch)
        #pragma unroll
        for (int fm = 0; fm < 2; ++fm) {
            uint2 pk;
            pk.x = (unsigned int)f2bf(pe[fm][0]) | ((unsigned int)f2bf(pe[fm][1]) << 16);
            pk.y = (unsigned int)f2bf(pe[fm][2]) | ((unsigned int)f2bf(pe[fm][3]) << 16);
            *(uint2*)&Ps[w][lr * 72 + fm * 16 + lk * 4] = pk;
        }
        // A-frag read-back (same-wave round trip; compiler orders via lgkmcnt)
        bf16x8 pa = *(const bf16x8*)&Ps[w][lr * 72 + lk * 8];

        // O[q=4lk+j][c=ns*16+lr] += P * V ; V rows = channels
        const unsigned short* Vc = &Vs[cur][0];
        __builtin_amdgcn_s_setprio(1);
        #pragma unroll
        for (int ns = 0; ns < 32; ++ns) {
            int c = ns * 16 + lr;
            int pos = (lk + ((c >> 1) & 3)) & 3;
            bf16x8 vf = *(const bf16x8*)&Vc[c * 32 + pos * 8];
            o[ns] = __builtin_amdgcn_mfma_f32_16x16x32_bf16(pa, vf, o[ns], 0, 0, 0);
        }
        __builtin_amdgcn_s_setprio(0);

        asm volatile("s_waitcnt lgkmcnt(0)" ::: "memory");
        __builtin_amdgcn_s_barrier();
    }

    float inv = 1.f / l;                     // for q-row = lr
    float f0 = __shfl(inv, 4 * lk + 0);
    float f1 = __shfl(inv, 4 * lk + 1);
    float f2 = __shfl(inv, 4 * lk + 2);
    float f3 = __shfl(inv, 4 * lk + 3);
    unsigned short* Hp = H + ((size_t)b * NSP + q0) * CD;
    #pragma unroll
    for (int ns = 0; ns < 32; ++ns) {
        Hp[(size_t)(lk * 4 + 0) * CD + ns * 16 + lr] = f2bf(o[ns][0] * f0);
        Hp[(size_t)(lk * 4 + 1) * CD + ns * 16 + lr] = f2bf(o[ns][1] * f1);
        Hp[(size_t)(lk * 4 + 2) * CD + ns * 16 + lr] = f2bf(o[ns][2] * f2);
        Hp[(size_t)(lk * 4 + 3) * CD + ns * 16 + lr] = f2bf(o[ns][3] * f3);
    }
}

extern "C" void kernel_launch(void* const* d_in, const int* in_sizes, int n_in,
                              void* d_out, int out_size, void* d_ws, size_t ws_size,
                              hipStream_t stream)
{
    const float* x  = (const float*)d_in[0];
    const float* Wq = (const float*)d_in[1];
    const float* bq = (const float*)d_in[2];
    const float* Wk = (const float*)d_in[3];
    const float* bk = (const float*)d_in[4];
    const float* Wv = (const float*)d_in[5];
    const float* bv = (const float*)d_in[6];
    const float* Wo = (const float*)d_in[7];
    const float* bo = (const float*)d_in[8];
    float* out = (float*)d_out;

    unsigned short* w   = (unsigned short*)d_ws;
    unsigned short* Wqb = w;
    unsigned short* Wkb = Wqb + 262144;
    unsigned short* Wvb = Wkb + 262144;
    unsigned short* Wob = Wvb + 262144;
    unsigned short* Xt  = Wob + 262144;      // [B][N][C]
    unsigned short* Qb  = Xt + 16777216;     // [B][N][C]
    unsigned short* Kb  = Qb + 16777216;     // [B][N][C]
    unsigned short* Vc  = Kb + 16777216;     // [B][C][N]
    unsigned short* Hb  = Xt;                // reuse Xt (dead after V gemm)

    cvt_w<<<1024, 256, 0, stream>>>(Wq, Wqb, 262144);
    cvt_w<<<1024, 256, 0, stream>>>(Wk, Wkb, 262144);
    cvt_w<<<1024, 256, 0, stream>>>(Wv, Wvb, 262144);
    cvt_w<<<1024, 256, 0, stream>>>(Wo, Wob, 262144);
    transpose_x<<<dim3(32, 16, 32), dim3(32, 8), 0, stream>>>(x, Xt);

    // Q = (Xt*Wq^T + bq) * C^-0.5 * log2(e)  (softmax runs in exp2 domain)
    gemm_bt<1, false, false><<<dim3(4, 256, 1), 256, 0, stream>>>(
        Xt, Wqb, Qb, bq, nullptr, 512, 512, 512, 512, 0, 0, 0, 0, 0.06376676f);
    gemm_bt<1, false, false><<<dim3(4, 256, 1), 256, 0, stream>>>(
        Xt, Wkb, Kb, bk, nullptr, 512, 512, 512, 512, 0, 0, 0, 0, 1.0f);

    // V in [C][N]: A=Wv [C,C], B=Xt_b [N,C], bias per-row(c)
    gemm_bt<2, false, false><<<dim3(8, 4, 32), 256, 0, stream>>>(
        Wvb, Xt, Vc, bv, nullptr, 512, 512, 512, 1024, 0, 524288, 524288, 0, 1.0f);

    // fused attention -> Hb [B][N][C]
    flash_attn<<<256, 512, 0, stream>>>(Qb, Kb, Vc, Hb);

    // out = Wo * H_b^T + bo(row) + x   [C][N] fp32
    gemm_bt<2, true, true><<<dim3(8, 4, 32), 256, 0, stream>>>(
        Wob, Hb, out, bo, x, 512, 512, 512, 1024,
        0, 524288, 524288, 524288, 1.0f);
}